// Round 7
// baseline (98.970 us; speedup 1.0000x reference)
//
#include <hip/hip_runtime.h>
#include <hip/hip_bf16.h>
#include <math.h>

#define B_  128
#define N_  16
#define T_  200
#define H_  64
#define J1  80
#define J2  40
#define NTILE 13
#define NEGV -4294967295.0f   // -2^32 + 1

typedef __attribute__((ext_vector_type(8))) short bf16x8;
typedef __attribute__((ext_vector_type(4))) float f32x4;

__device__ __forceinline__ float sigmoidf_(float x) {
    return 1.0f / (1.0f + __expf(-x));
}
// branch-free RNE f32->bf16 (finite inputs only)
__device__ __forceinline__ short f2b(float x) {
    unsigned u = __float_as_uint(x);
    return (short)((u + 0x7FFF + ((u >> 16) & 1)) >> 16);
}
__device__ __forceinline__ unsigned pack2(float a, float b) {
    return (unsigned)(unsigned short)f2b(a) | ((unsigned)(unsigned short)f2b(b) << 16);
}

// ---- fused prep: ONE dispatch, 4 independent block ranges ---------------
// [0,160):        QW[bn][j]  = b1[j] + sum_h q*(W1a+W1c)        (2048*20 thr)
// [160,5280):     Bnf frag-ordered bf16: q[h]*W1d[h][j]+W1b-W1c (2048*640 thr)
// [5280,5696):    keys -> frag-ordered bf16 A-frags             (128*13*64 thr)
// [5696,5705):    W2 -> frag-ordered bf16 (k pad 96, m pad 48)  (2304 thr)
#define QW_BLK   160
#define BNF_BLK  5120
#define KBF_BLK  416
#define W2F_BLK  9
__global__ void prep_all(const float* __restrict__ queries,
                         const float* __restrict__ keys,
                         const float* __restrict__ W1,
                         const float* __restrict__ b1,
                         const float* __restrict__ W2,
                         float* __restrict__ QW,
                         bf16x8* __restrict__ Bnf,
                         bf16x8* __restrict__ kbf0, bf16x8* __restrict__ kbf1,
                         unsigned* __restrict__ W2F) {
    const int blk = blockIdx.x, tid = threadIdx.x;
    if (blk < QW_BLK) {
        int idx = blk * 256 + tid;                 // (bn, j/4), exact fit
        int bn = idx / 20, j = (idx % 20) * 4;
        float4 acc = *(const float4*)(b1 + j);
        const float* qp = queries + bn * H_;
        for (int h = 0; h < H_; ++h) {
            float qh = qp[h];
            float4 wa = *(const float4*)(W1 + h * J1 + j);
            float4 wc = *(const float4*)(W1 + (128 + h) * J1 + j);
            acc.x = fmaf(qh, wa.x + wc.x, acc.x);
            acc.y = fmaf(qh, wa.y + wc.y, acc.y);
            acc.z = fmaf(qh, wa.z + wc.z, acc.z);
            acc.w = fmaf(qh, wa.w + wc.w, acc.w);
        }
        *(float4*)(QW + bn * J1 + j) = acc;
    } else if (blk < QW_BLK + BNF_BLK) {
        // thread per (bn, f, l): 8 shorts, h=(f&1)*32+(l>>4)*8+r, j=(f>>1)*16+(l&15)
        int idx = (blk - QW_BLK) * 256 + tid;      // exact fit
        int l = idx & 63, f = (idx >> 6) % 10, bn = idx / 640;
        int j  = (f >> 1) * 16 + (l & 15);
        int h0 = (f & 1) * 32 + (l >> 4) * 8;
        const float* qp = queries + bn * H_ + h0;
        float v[8];
        #pragma unroll
        for (int r = 0; r < 8; ++r) {
            int h = h0 + r;
            float wd = W1[(192 + h) * J1 + j];
            float wb = W1[( 64 + h) * J1 + j];
            float wc = W1[(128 + h) * J1 + j];
            v[r] = fmaf(qp[r], wd, wb - wc);
        }
        uint4 o = make_uint4(pack2(v[0], v[1]), pack2(v[2], v[3]),
                             pack2(v[4], v[5]), pack2(v[6], v[7]));
        *(uint4*)(Bnf + idx) = o;                  // coalesced 16B
    } else if (blk < QW_BLK + BNF_BLK + KBF_BLK) {
        int idx = (blk - QW_BLK - BNF_BLK) * 256 + tid;   // (b*13+mt)*64+l, exact
        int l  = idx & 63, bm = idx >> 6;
        int mt = bm % NTILE, b = bm / NTILE;
        int t  = mt * 16 + (l & 15); if (t > T_ - 1) t = T_ - 1;
        int rg = l >> 4;
        const float* kr = keys + ((size_t)(b * T_ + t)) * H_ + 8 * rg;
        float4 a0 = *(const float4*)(kr);
        float4 a1 = *(const float4*)(kr + 4);
        float4 a2 = *(const float4*)(kr + 32);
        float4 a3 = *(const float4*)(kr + 36);
        bf16x8 f0, f1;
        f0[0] = f2b(a0.x); f0[1] = f2b(a0.y); f0[2] = f2b(a0.z); f0[3] = f2b(a0.w);
        f0[4] = f2b(a1.x); f0[5] = f2b(a1.y); f0[6] = f2b(a1.z); f0[7] = f2b(a1.w);
        f1[0] = f2b(a2.x); f1[1] = f2b(a2.y); f1[2] = f2b(a2.z); f1[3] = f2b(a2.w);
        f1[4] = f2b(a3.x); f1[5] = f2b(a3.y); f1[6] = f2b(a3.z); f1[7] = f2b(a3.w);
        kbf0[idx] = f0; kbf1[idx] = f1;
    } else {
        int idx = (blk - QW_BLK - BNF_BLK - KBF_BLK) * 256 + tid;
        if (idx < 9 * 64 * 4) {
            int rp = idx & 3;
            int l  = (idx >> 2) & 63;
            int f  = idx >> 8;
            int m  = (f / 3) * 16 + (l & 15);
            int k0 = (f % 3) * 32 + 8 * (l >> 4) + 2 * rp;
            float a = (k0     < J1 && m < J2) ? W2[k0 * J2 + m]       : 0.0f;
            float b = (k0 + 1 < J1 && m < J2) ? W2[(k0 + 1) * J2 + m] : 0.0f;
            W2F[idx] = pack2(a, b);
        }
    }
}

// ---- fused main: block per bn, 8 waves; Bn/W2 in LDS (read once per bn) --
// Waves tile-parallel over the 13 row-tiles (<=2 tiles/wave), then in-block
// softmax + weighted-sum. 2 dispatches total.
__global__ __launch_bounds__(512) void attn_fused(
        const float* __restrict__ keys, const int* __restrict__ keys_length,
        const float* __restrict__ QW,
        const bf16x8* __restrict__ Bnf,
        const bf16x8* __restrict__ kbf0, const bf16x8* __restrict__ kbf1,
        const bf16x8* __restrict__ W2F,
        const float* __restrict__ b2, const float* __restrict__ W3,
        const float* __restrict__ b3,
        float* __restrict__ out) {
    const int tid  = threadIdx.x;
    const int lane = tid & 63, wv = tid >> 6;            // 8 waves
    const int bn   = (blockIdx.x & 7) * 256 + (blockIdx.x >> 3);  // XCD swizzle
    const int b    = bn >> 4;
    const int cl   = lane & 15, rg = lane >> 4;

    __shared__ __align__(16) short BnL[10 * 64 * 8];     // 10240 B
    __shared__ __align__(16) short W2L[9 * 64 * 8];      //  9216 B
    __shared__ __align__(16) short X1[8][16][104];       // 26624 B, per-wave slice
    __shared__ float z3s[NTILE * 16];                    //   832 B
    __shared__ float wsm[T_];
    __shared__ float part[512];
    __shared__ float red[16];

    // cooperative loads: Bn frags (640x16B) + W2 frags (576x16B), coalesced
    {
        const bf16x8* bsrc = Bnf + (size_t)bn * 640;
        for (int i = tid; i < 640; i += 512) ((bf16x8*)BnL)[i] = bsrc[i];
        for (int i = tid; i < 576; i += 512) ((bf16x8*)W2L)[i] = W2F[i];
    }
    // zero own-wave X1 k-pad cols 80..95 (wave-coherent, no barrier needed)
    #pragma unroll
    for (int i = 0; i < 4; ++i)
        X1[wv][rg + 4 * i][80 + cl] = 0;

    // per-lane constants (held across tile loop)
    float qwv[5];
    #pragma unroll
    for (int nt = 0; nt < 5; ++nt) qwv[nt] = QW[bn * J1 + cl + 16 * nt];
    float b2v[3], w3v[3];
    #pragma unroll
    for (int nt = 0; nt < 3; ++nt) {
        int m  = cl + 16 * nt;
        int mc = m < J2 ? m : J2 - 1;
        b2v[nt] = b2[mc];
        w3v[nt] = (m < J2) ? W3[mc] : 0.0f;
    }
    const float b3v = b3[0];
    __syncthreads();

    // ---- tile loop: wave wv handles mt = wv, wv+8 ----
    for (int mt = wv; mt < NTILE; mt += 8) {
        const int t0 = mt * 16;
        bf16x8 a0 = kbf0[(b * NTILE + mt) * 64 + lane];  // L2-hot 16B
        bf16x8 a1 = kbf1[(b * NTILE + mt) * 64 + lane];

        // layer 1: Z1 = K @ Bn + QW
        f32x4 acc[5];
        #pragma unroll
        for (int nt = 0; nt < 5; ++nt) {
            float qv = qwv[nt];
            acc[nt][0] = qv; acc[nt][1] = qv; acc[nt][2] = qv; acc[nt][3] = qv;
        }
        #pragma unroll
        for (int nt = 0; nt < 5; ++nt) {
            bf16x8 b0 = *(const bf16x8*)&BnL[((nt * 2 + 0) * 64 + lane) * 8];
            bf16x8 b1f = *(const bf16x8*)&BnL[((nt * 2 + 1) * 64 + lane) * 8];
            acc[nt] = __builtin_amdgcn_mfma_f32_16x16x32_bf16(a0, b0,  acc[nt], 0, 0, 0);
            acc[nt] = __builtin_amdgcn_mfma_f32_16x16x32_bf16(a1, b1f, acc[nt], 0, 0, 0);
        }

        // sigmoid -> X1 (C layout: row = rg*4+i, col = cl+16nt)
        #pragma unroll
        for (int nt = 0; nt < 5; ++nt)
            #pragma unroll
            for (int i = 0; i < 4; ++i)
                X1[wv][rg * 4 + i][cl + 16 * nt] = f2b(sigmoidf_(acc[nt][i]));

        // layer 2: Z2 = X1 @ W2 + b2 (A from own-wave LDS slice)
        f32x4 acc2[3];
        #pragma unroll
        for (int nt = 0; nt < 3; ++nt) {
            float bv = b2v[nt];
            acc2[nt][0] = bv; acc2[nt][1] = bv; acc2[nt][2] = bv; acc2[nt][3] = bv;
        }
        #pragma unroll
        for (int ks = 0; ks < 3; ++ks) {
            bf16x8 a2 = *(const bf16x8*)&X1[wv][cl][8 * rg + 32 * ks];
            bf16x8 w0 = *(const bf16x8*)&W2L[((0 * 3 + ks) * 64 + lane) * 8];
            bf16x8 w1 = *(const bf16x8*)&W2L[((1 * 3 + ks) * 64 + lane) * 8];
            bf16x8 w2 = *(const bf16x8*)&W2L[((2 * 3 + ks) * 64 + lane) * 8];
            acc2[0] = __builtin_amdgcn_mfma_f32_16x16x32_bf16(a2, w0, acc2[0], 0, 0, 0);
            acc2[1] = __builtin_amdgcn_mfma_f32_16x16x32_bf16(a2, w1, acc2[1], 0, 0, 0);
            acc2[2] = __builtin_amdgcn_mfma_f32_16x16x32_bf16(a2, w2, acc2[2], 0, 0, 0);
        }

        // layer 3: z3[t] = sum_m sigmoid(z2[t][m]) * W3[m] + b3
        float p0 = 0.f, p1 = 0.f, p2 = 0.f, p3 = 0.f;
        #pragma unroll
        for (int nt = 0; nt < 3; ++nt) {
            p0 = fmaf(sigmoidf_(acc2[nt][0]), w3v[nt], p0);
            p1 = fmaf(sigmoidf_(acc2[nt][1]), w3v[nt], p1);
            p2 = fmaf(sigmoidf_(acc2[nt][2]), w3v[nt], p2);
            p3 = fmaf(sigmoidf_(acc2[nt][3]), w3v[nt], p3);
        }
        #pragma unroll
        for (int off = 1; off < 16; off <<= 1) {
            p0 += __shfl_xor(p0, off);
            p1 += __shfl_xor(p1, off);
            p2 += __shfl_xor(p2, off);
            p3 += __shfl_xor(p3, off);
        }
        if (cl == 0) {
            z3s[t0 + rg * 4 + 0] = p0 + b3v;
            z3s[t0 + rg * 4 + 1] = p1 + b3v;
            z3s[t0 + rg * 4 + 2] = p2 + b3v;
            z3s[t0 + rg * 4 + 3] = p3 + b3v;
        }
    }
    __syncthreads();

    // ---- mask + scale + softmax (8-wave reduction) ----
    const int L = keys_length[b];
    float s = (tid < T_) ? ((tid < L) ? z3s[tid] : NEGV) * 0.125f : -3.0e38f;

    float mx = s;
    #pragma unroll
    for (int off = 32; off > 0; off >>= 1) mx = fmaxf(mx, __shfl_xor(mx, off));
    if (lane == 0) red[wv] = mx;
    __syncthreads();
    mx = red[0];
    #pragma unroll
    for (int w = 1; w < 8; ++w) mx = fmaxf(mx, red[w]);

    float e = (tid < T_) ? __expf(s - mx) : 0.0f;
    float sm = e;
    #pragma unroll
    for (int off = 32; off > 0; off >>= 1) sm += __shfl_xor(sm, off);
    if (lane == 0) red[8 + wv] = sm;
    __syncthreads();
    sm = red[8];
    #pragma unroll
    for (int w = 1; w < 8; ++w) sm += red[8 + w];

    if (tid < T_) wsm[tid] = e / sm;
    __syncthreads();

    // ---- out[h] = sum_t w[t] * keys[b][t][h]; 8 waves x 25 t's ----
    const float* kb = keys + (size_t)b * T_ * H_;
    {
        float acc = 0.f;
        int tb = wv * 25;
        #pragma unroll 5
        for (int t = tb; t < tb + 25; ++t)
            acc = fmaf(wsm[t], kb[(size_t)t * H_ + lane], acc);
        part[tid] = acc;
    }
    __syncthreads();
    if (tid < 64) {
        float o = 0.f;
        #pragma unroll
        for (int w = 0; w < 8; ++w) o += part[w * 64 + tid];
        out[bn * H_ + tid] = o;
    }
}

// --- fallback (no workspace): round-3 verified pure-VALU kernel ----------
__global__ __launch_bounds__(256, 3) void attn_nows(
        const float* __restrict__ queries, const float* __restrict__ keys,
        const int*   __restrict__ keys_length,
        const float* __restrict__ W1, const float* __restrict__ b1,
        const float* __restrict__ W2, const float* __restrict__ b2,
        const float* __restrict__ W3, const float* __restrict__ b3,
        float* __restrict__ out) {
    const int tid = threadIdx.x;
    const int bn = (blockIdx.x & 7) * 256 + (blockIdx.x >> 3);
    const int b  = bn >> 4;

    __shared__ float kT[H_][T_ + 1];
    __shared__ float wsm[T_];
    __shared__ float part[256];
    __shared__ float red[8];
    __shared__ float QWq[J1];

    for (int idx = tid; idx < T_ * H_; idx += 256) {
        int t = idx >> 6, h = idx & 63;
        kT[h][t] = keys[(b * T_ + t) * H_ + h];
    }
    if (tid < J1) {
        float acc = b1[tid];
        const float* qp = queries + bn * H_;
        for (int h = 0; h < H_; ++h)
            acc = fmaf(qp[h], W1[h * J1 + tid] + W1[(128 + h) * J1 + tid], acc);
        QWq[tid] = acc;
    }
    __syncthreads();

    const int tt = (tid < T_) ? tid : 0;
    const float* qp = queries + bn * H_;

    float qk[H_];
    #pragma unroll
    for (int h = 0; h < H_; ++h) qk[h] = qp[h] * kT[h][tt];

    float z2[J2];
    #pragma unroll
    for (int m = 0; m < J2; ++m) z2[m] = b2[m];

    #pragma unroll 1
    for (int c = 0; c < 4; ++c) {
        const int j0 = c * 20;
        float z1c[20];
        #pragma unroll
        for (int j = 0; j < 20; ++j) z1c[j] = QWq[j0 + j];
        #pragma unroll
        for (int h = 0; h < H_; ++h) {
            float kh = kT[h][tt];
            const float* Wd = W1 + (192 + h) * J1 + j0;
            const float* Wb = W1 + (64 + h) * J1 + j0;
            const float* Wc = W1 + (128 + h) * J1 + j0;
            #pragma unroll
            for (int j = 0; j < 20; ++j)
                z1c[j] = fmaf(qk[h], Wd[j], fmaf(kh, Wb[j] - Wc[j], z1c[j]));
        }
        #pragma unroll
        for (int j = 0; j < 20; ++j) {
            float x = sigmoidf_(z1c[j]);
            const float* w2 = W2 + (j0 + j) * J2;
            #pragma unroll
            for (int m = 0; m < J2; ++m) z2[m] = fmaf(x, w2[m], z2[m]);
        }
    }

    float z3 = b3[0];
    #pragma unroll
    for (int m = 0; m < J2; ++m) z3 = fmaf(sigmoidf_(z2[m]), W3[m], z3);

    const int L = keys_length[b];
    float s = (tid < T_) ? ((tid < L) ? z3 : NEGV) * 0.125f : -3.0e38f;

    float mx = s;
    #pragma unroll
    for (int off = 32; off > 0; off >>= 1) mx = fmaxf(mx, __shfl_xor(mx, off));
    if ((tid & 63) == 0) red[tid >> 6] = mx;
    __syncthreads();
    mx = fmaxf(fmaxf(red[0], red[1]), fmaxf(red[2], red[3]));

    float e = (tid < T_) ? __expf(s - mx) : 0.0f;
    float sm = e;
    #pragma unroll
    for (int off = 32; off > 0; off >>= 1) sm += __shfl_xor(sm, off);
    __syncthreads();
    if ((tid & 63) == 0) red[4 + (tid >> 6)] = sm;
    __syncthreads();
    sm = red[4] + red[5] + red[6] + red[7];

    if (tid < T_) wsm[tid] = e / sm;
    __syncthreads();

    {
        int h = tid & 63, p = tid >> 6;
        float acc = 0.f;
        int t0 = p * 50;
        for (int t = t0; t < t0 + 50; ++t)
            acc = fmaf(wsm[t], kT[h][t], acc);
        part[tid] = acc;
    }
    __syncthreads();
    if (tid < 64) {
        out[bn * H_ + tid] = part[tid] + part[64 + tid] + part[128 + tid] + part[192 + tid];
    }
}

extern "C" void kernel_launch(void* const* d_in, const int* in_sizes, int n_in,
                              void* d_out, int out_size, void* d_ws, size_t ws_size,
                              hipStream_t stream) {
    const float* queries = (const float*)d_in[0];
    const float* keys    = (const float*)d_in[1];
    const int*   klen    = (const int*)  d_in[2];
    const float* W1 = (const float*)d_in[3];
    const float* b1 = (const float*)d_in[4];
    const float* W2 = (const float*)d_in[5];
    const float* b2 = (const float*)d_in[6];
    const float* W3 = (const float*)d_in[7];
    const float* b3 = (const float*)d_in[8];
    float* out = (float*)d_out;

    // ws layout (16B-aligned segments):
    // QW  [2048*80 f32]     =    655,360 B
    // kbf0[128*13*64 x 16B] =  1,703,936 B
    // kbf1[same]            =  1,703,936 B
    // Bnf [2048*640 x 16B]  = 20,971,520 B
    // W2F [2304 u32]        =      9,216 B
    const size_t nkbf = (size_t)B_ * NTILE * 64;
    const size_t need = 655360 + 2 * 1703936 + 20971520 + 9216;

    if (ws_size >= need) {
        float*  QW   = (float*)d_ws;
        bf16x8* kbf0 = (bf16x8*)((char*)d_ws + 655360);
        bf16x8* kbf1 = kbf0 + nkbf;
        bf16x8* Bnf  = kbf1 + nkbf;
        unsigned* W2F = (unsigned*)((char*)Bnf + 20971520);

        prep_all<<<dim3(QW_BLK + BNF_BLK + KBF_BLK + W2F_BLK), dim3(256), 0, stream>>>(
            queries, keys, W1, b1, W2, QW, Bnf, kbf0, kbf1, W2F);
        attn_fused<<<dim3(B_ * N_), dim3(512), 0, stream>>>(
            keys, klen, QW, Bnf, kbf0, kbf1, (const bf16x8*)W2F, b2, W3, b3, out);
    } else {
        attn_nows<<<dim3(B_ * N_), dim3(256), 0, stream>>>(
            queries, keys, klen, W1, b1, W2, b2, W3, b3, out);
    }
}

// Round 8
// 98.774 us; speedup vs baseline: 1.0020x; 1.0020x over previous
//
#include <hip/hip_runtime.h>
#include <hip/hip_bf16.h>
#include <math.h>

#define B_  128
#define N_  16
#define T_  200
#define H_  64
#define J1  80
#define J2  40
#define NTILE 13
#define NEGV -4294967295.0f   // -2^32 + 1

typedef __attribute__((ext_vector_type(8))) short bf16x8;
typedef __attribute__((ext_vector_type(4))) float f32x4;

__device__ __forceinline__ float sigmoidf_(float x) {
    return 1.0f / (1.0f + __expf(-x));
}
// branch-free RNE f32->bf16 (finite inputs only)
__device__ __forceinline__ short f2b(float x) {
    unsigned u = __float_as_uint(x);
    return (short)((u + 0x7FFF + ((u >> 16) & 1)) >> 16);
}
__device__ __forceinline__ unsigned pack2(float a, float b) {
    return (unsigned)(unsigned short)f2b(a) | ((unsigned)(unsigned short)f2b(b) << 16);
}

// ---- prep1: QW | w1df/wbcf (frag-ordered f32) | kbf | W2F ---------------
// [0,160):   QW[bn][j] = b1[j] + sum_h q*(W1a+W1c)     (2048*20 thr, exact)
// [160,163): w1df/wbcf frag-ordered f32                 (640 thr)
// [163,267): keys -> frag-ordered bf16 A-frags          (26624 thr, exact)
// [267,276): W2 -> frag-ordered bf16                    (2304 thr)
#define P_QW 160
#define P_WF 3
#define P_KB 104
#define P_W2 9
__global__ void prep1(const float* __restrict__ queries,
                      const float* __restrict__ keys,
                      const float* __restrict__ W1,
                      const float* __restrict__ b1,
                      const float* __restrict__ W2,
                      float* __restrict__ QW,
                      float* __restrict__ w1df, float* __restrict__ wbcf,
                      bf16x8* __restrict__ kbf0, bf16x8* __restrict__ kbf1,
                      unsigned* __restrict__ W2F) {
    const int blk = blockIdx.x, tid = threadIdx.x;
    if (blk < P_QW) {
        int idx = blk * 256 + tid;                 // (bn, j/4)
        int bn = idx / 20, j = (idx % 20) * 4;
        float4 acc = *(const float4*)(b1 + j);
        const float* qp = queries + bn * H_;
        for (int h = 0; h < H_; ++h) {
            float qh = qp[h];
            float4 wa = *(const float4*)(W1 + h * J1 + j);
            float4 wc = *(const float4*)(W1 + (128 + h) * J1 + j);
            acc.x = fmaf(qh, wa.x + wc.x, acc.x);
            acc.y = fmaf(qh, wa.y + wc.y, acc.y);
            acc.z = fmaf(qh, wa.z + wc.z, acc.z);
            acc.w = fmaf(qh, wa.w + wc.w, acc.w);
        }
        *(float4*)(QW + bn * J1 + j) = acc;
    } else if (blk < P_QW + P_WF) {
        int idx = (blk - P_QW) * 256 + tid;        // (f,l), 640 threads
        if (idx < 640) {
            int l = idx & 63, f = idx >> 6;
            int j  = (f >> 1) * 16 + (l & 15);
            int h0 = (f & 1) * 32 + ((l >> 4) << 3);
            #pragma unroll
            for (int r = 0; r < 8; ++r) {
                int h = h0 + r;
                w1df[idx * 8 + r] = W1[(192 + h) * J1 + j];
                wbcf[idx * 8 + r] = W1[(64 + h) * J1 + j] - W1[(128 + h) * J1 + j];
            }
        }
    } else if (blk < P_QW + P_WF + P_KB) {
        int idx = (blk - P_QW - P_WF) * 256 + tid; // (b*13+mt)*64+l, exact
        int l  = idx & 63, bm = idx >> 6;
        int mt = bm % NTILE, b = bm / NTILE;
        int t  = mt * 16 + (l & 15); if (t > T_ - 1) t = T_ - 1;
        int rg = l >> 4;
        const float* kr = keys + ((size_t)(b * T_ + t)) * H_ + 8 * rg;
        float4 a0 = *(const float4*)(kr);
        float4 a1 = *(const float4*)(kr + 4);
        float4 a2 = *(const float4*)(kr + 32);
        float4 a3 = *(const float4*)(kr + 36);
        bf16x8 f0, f1;
        f0[0] = f2b(a0.x); f0[1] = f2b(a0.y); f0[2] = f2b(a0.z); f0[3] = f2b(a0.w);
        f0[4] = f2b(a1.x); f0[5] = f2b(a1.y); f0[6] = f2b(a1.z); f0[7] = f2b(a1.w);
        f1[0] = f2b(a2.x); f1[1] = f2b(a2.y); f1[2] = f2b(a2.z); f1[3] = f2b(a2.w);
        f1[4] = f2b(a3.x); f1[5] = f2b(a3.y); f1[6] = f2b(a3.z); f1[7] = f2b(a3.w);
        kbf0[idx] = f0; kbf1[idx] = f1;
    } else {
        int idx = (blk - P_QW - P_WF - P_KB) * 256 + tid;
        if (idx < 9 * 64 * 4) {
            int rp = idx & 3;
            int l  = (idx >> 2) & 63;
            int f  = idx >> 8;
            int m  = (f / 3) * 16 + (l & 15);
            int k0 = (f % 3) * 32 + 8 * (l >> 4) + 2 * rp;
            float a = (k0     < J1 && m < J2) ? W2[k0 * J2 + m]       : 0.0f;
            float b = (k0 + 1 < J1 && m < J2) ? W2[(k0 + 1) * J2 + m] : 0.0f;
            W2F[idx] = pack2(a, b);
        }
    }
}

// ---- prep2: Bnf[bn,f,l] = f2b(q[bn,h]*w1df + wbcf) — pure streaming -----
__global__ void prep2(const float* __restrict__ queries,
                      const float* __restrict__ w1df,
                      const float* __restrict__ wbcf,
                      uint4* __restrict__ Bnf) {
    int idx = blockIdx.x * 256 + threadIdx.x;      // 2048*640, exact
    int rem = idx % 640, bn = idx / 640;
    int f = rem >> 6, l = rem & 63;
    int h0 = (f & 1) * 32 + ((l >> 4) << 3);
    float4 w0 = *(const float4*)(w1df + rem * 8);
    float4 w1 = *(const float4*)(w1df + rem * 8 + 4);
    float4 c0 = *(const float4*)(wbcf + rem * 8);
    float4 c1 = *(const float4*)(wbcf + rem * 8 + 4);
    const float* qp = queries + bn * H_ + h0;
    float4 q0 = *(const float4*)(qp);
    float4 q1 = *(const float4*)(qp + 4);
    uint4 o;
    o.x = pack2(fmaf(q0.x, w0.x, c0.x), fmaf(q0.y, w0.y, c0.y));
    o.y = pack2(fmaf(q0.z, w0.z, c0.z), fmaf(q0.w, w0.w, c0.w));
    o.z = pack2(fmaf(q1.x, w1.x, c1.x), fmaf(q1.y, w1.y, c1.y));
    o.w = pack2(fmaf(q1.z, w1.z, c1.z), fmaf(q1.w, w1.w, c1.w));
    Bnf[idx] = o;                                  // coalesced 16B
}

// ---- main: block per bn, 4 waves; wave g owns tiles 4g..4g+3 as 2 pairs.
// Each Bn fragment is loaded once per pair and feeds 2 M-tiles (4 indep
// MFMA chains). No barriers until softmax. Fused softmax + PV.
__global__ __launch_bounds__(256, 4) void attn_b4(
        const float* __restrict__ keys, const int* __restrict__ keys_length,
        const float* __restrict__ QW,
        const bf16x8* __restrict__ Bnf,
        const bf16x8* __restrict__ kbf0, const bf16x8* __restrict__ kbf1,
        const bf16x8* __restrict__ W2F,
        const float* __restrict__ b2, const float* __restrict__ W3,
        const float* __restrict__ b3,
        float* __restrict__ out) {
    const int tid  = threadIdx.x;
    const int lane = tid & 63, wv = tid >> 6;            // 4 waves
    const int bn   = (blockIdx.x & 7) * 256 + (blockIdx.x >> 3);  // XCD swizzle
    const int b    = bn >> 4;
    const int cl   = lane & 15, rg = lane >> 4;

    __shared__ __align__(16) short X1[4][16][104];       // one slice per wave
    __shared__ float z3s[NTILE * 16];
    __shared__ float wsm[T_];
    __shared__ float part[256];
    __shared__ float red[8];

    // zero own-wave X1 k-pad cols 80..95 (wave-local, in-order LDS)
    #pragma unroll
    for (int i = 0; i < 4; ++i)
        X1[wv][rg + 4 * i][80 + cl] = 0;

    float qwv[5];
    #pragma unroll
    for (int nt = 0; nt < 5; ++nt) qwv[nt] = QW[bn * J1 + cl + 16 * nt];
    float b2v[3], w3v[3];
    #pragma unroll
    for (int nt = 0; nt < 3; ++nt) {
        int m  = cl + 16 * nt;
        int mc = m < J2 ? m : J2 - 1;
        b2v[nt] = b2[mc];
        w3v[nt] = (m < J2) ? W3[mc] : 0.0f;
    }
    const float b3v = b3[0];
    const bf16x8* bnp = Bnf + (size_t)bn * 640;

    #pragma unroll 1
    for (int p = 0; p < 2; ++p) {
        const int i0  = wv * 4 + 2 * p;
        const int mt0 = i0     < 12 ? i0     : 12;       // clamp: g=3 redoes tile 12
        const int mt1 = i0 + 1 < 12 ? i0 + 1 : 12;       // (identical rewrite, benign)
        bf16x8 a00 = kbf0[(b * NTILE + mt0) * 64 + lane];
        bf16x8 a01 = kbf1[(b * NTILE + mt0) * 64 + lane];
        bf16x8 a10 = kbf0[(b * NTILE + mt1) * 64 + lane];
        bf16x8 a11 = kbf1[(b * NTILE + mt1) * 64 + lane];

        f32x4 acc[2][5];
        #pragma unroll
        for (int nt = 0; nt < 5; ++nt) {
            float qv = qwv[nt];
            acc[0][nt][0] = qv; acc[0][nt][1] = qv; acc[0][nt][2] = qv; acc[0][nt][3] = qv;
            acc[1][nt][0] = qv; acc[1][nt][1] = qv; acc[1][nt][2] = qv; acc[1][nt][3] = qv;
        }
        #pragma unroll 2
        for (int nt = 0; nt < 5; ++nt) {
            bf16x8 b0 = bnp[(2 * nt + 0) * 64 + lane];   // L2, used by both tiles
            bf16x8 b1 = bnp[(2 * nt + 1) * 64 + lane];
            acc[0][nt] = __builtin_amdgcn_mfma_f32_16x16x32_bf16(a00, b0, acc[0][nt], 0, 0, 0);
            acc[1][nt] = __builtin_amdgcn_mfma_f32_16x16x32_bf16(a10, b0, acc[1][nt], 0, 0, 0);
            acc[0][nt] = __builtin_amdgcn_mfma_f32_16x16x32_bf16(a01, b1, acc[0][nt], 0, 0, 0);
            acc[1][nt] = __builtin_amdgcn_mfma_f32_16x16x32_bf16(a11, b1, acc[1][nt], 0, 0, 0);
        }

        // per-tile epilogue (X1 slice reused sequentially; in-order per wave)
        #pragma unroll
        for (int ti = 0; ti < 2; ++ti) {
            const int mte = (ti == 0) ? mt0 : mt1;
            #pragma unroll
            for (int nt = 0; nt < 5; ++nt)
                #pragma unroll
                for (int i = 0; i < 4; ++i)
                    X1[wv][rg * 4 + i][cl + 16 * nt] = f2b(sigmoidf_(acc[ti][nt][i]));

            f32x4 acc2[3];
            #pragma unroll
            for (int nt = 0; nt < 3; ++nt) {
                float bv = b2v[nt];
                acc2[nt][0] = bv; acc2[nt][1] = bv; acc2[nt][2] = bv; acc2[nt][3] = bv;
            }
            #pragma unroll
            for (int ks = 0; ks < 3; ++ks) {
                bf16x8 a2 = *(const bf16x8*)&X1[wv][cl][8 * rg + 32 * ks];
                acc2[0] = __builtin_amdgcn_mfma_f32_16x16x32_bf16(a2, W2F[(0 + ks) * 64 + lane], acc2[0], 0, 0, 0);
                acc2[1] = __builtin_amdgcn_mfma_f32_16x16x32_bf16(a2, W2F[(3 + ks) * 64 + lane], acc2[1], 0, 0, 0);
                acc2[2] = __builtin_amdgcn_mfma_f32_16x16x32_bf16(a2, W2F[(6 + ks) * 64 + lane], acc2[2], 0, 0, 0);
            }

            float p0 = 0.f, p1 = 0.f, p2 = 0.f, p3 = 0.f;
            #pragma unroll
            for (int nt = 0; nt < 3; ++nt) {
                p0 = fmaf(sigmoidf_(acc2[nt][0]), w3v[nt], p0);
                p1 = fmaf(sigmoidf_(acc2[nt][1]), w3v[nt], p1);
                p2 = fmaf(sigmoidf_(acc2[nt][2]), w3v[nt], p2);
                p3 = fmaf(sigmoidf_(acc2[nt][3]), w3v[nt], p3);
            }
            #pragma unroll
            for (int off = 1; off < 16; off <<= 1) {
                p0 += __shfl_xor(p0, off);
                p1 += __shfl_xor(p1, off);
                p2 += __shfl_xor(p2, off);
                p3 += __shfl_xor(p3, off);
            }
            if (cl == 0) {
                z3s[mte * 16 + rg * 4 + 0] = p0 + b3v;
                z3s[mte * 16 + rg * 4 + 1] = p1 + b3v;
                z3s[mte * 16 + rg * 4 + 2] = p2 + b3v;
                z3s[mte * 16 + rg * 4 + 3] = p3 + b3v;
            }
        }
    }
    __syncthreads();

    // ---- mask + scale + softmax (thread tid owns t = tid) ----
    const int L = keys_length[b];
    float s = (tid < T_) ? ((tid < L) ? z3s[tid] : NEGV) * 0.125f : -3.0e38f;

    float mx = s;
    #pragma unroll
    for (int off = 32; off > 0; off >>= 1) mx = fmaxf(mx, __shfl_xor(mx, off));
    if ((tid & 63) == 0) red[tid >> 6] = mx;
    __syncthreads();
    mx = fmaxf(fmaxf(red[0], red[1]), fmaxf(red[2], red[3]));

    float e = (tid < T_) ? __expf(s - mx) : 0.0f;
    float sm = e;
    #pragma unroll
    for (int off = 32; off > 0; off >>= 1) sm += __shfl_xor(sm, off);
    __syncthreads();
    if ((tid & 63) == 0) red[4 + (tid >> 6)] = sm;
    __syncthreads();
    sm = red[4] + red[5] + red[6] + red[7];

    if (tid < T_) wsm[tid] = e / sm;
    __syncthreads();

    // ---- out[h] = sum_t w[t] * keys[b][t][h] (L2-hot, coalesced) ----
    const float* kb = keys + (size_t)b * T_ * H_;
    {
        int h = tid & 63, pw = tid >> 6;
        float acc = 0.f;
        int tb = pw * 50;
        #pragma unroll 5
        for (int t = tb; t < tb + 50; ++t)
            acc = fmaf(wsm[t], kb[(size_t)t * H_ + h], acc);
        part[tid] = acc;
    }
    __syncthreads();
    if (tid < 64) {
        out[bn * H_ + tid] = part[tid] + part[64 + tid] + part[128 + tid] + part[192 + tid];
    }
}

// --- fallback (no workspace): round-3 verified pure-VALU kernel ----------
__global__ __launch_bounds__(256, 3) void attn_nows(
        const float* __restrict__ queries, const float* __restrict__ keys,
        const int*   __restrict__ keys_length,
        const float* __restrict__ W1, const float* __restrict__ b1,
        const float* __restrict__ W2, const float* __restrict__ b2,
        const float* __restrict__ W3, const float* __restrict__ b3,
        float* __restrict__ out) {
    const int tid = threadIdx.x;
    const int bn = (blockIdx.x & 7) * 256 + (blockIdx.x >> 3);
    const int b  = bn >> 4;

    __shared__ float kT[H_][T_ + 1];
    __shared__ float wsm[T_];
    __shared__ float part[256];
    __shared__ float red[8];
    __shared__ float QWq[J1];

    for (int idx = tid; idx < T_ * H_; idx += 256) {
        int t = idx >> 6, h = idx & 63;
        kT[h][t] = keys[(b * T_ + t) * H_ + h];
    }
    if (tid < J1) {
        float acc = b1[tid];
        const float* qp = queries + bn * H_;
        for (int h = 0; h < H_; ++h)
            acc = fmaf(qp[h], W1[h * J1 + tid] + W1[(128 + h) * J1 + tid], acc);
        QWq[tid] = acc;
    }
    __syncthreads();

    const int tt = (tid < T_) ? tid : 0;
    const float* qp = queries + bn * H_;

    float qk[H_];
    #pragma unroll
    for (int h = 0; h < H_; ++h) qk[h] = qp[h] * kT[h][tt];

    float z2[J2];
    #pragma unroll
    for (int m = 0; m < J2; ++m) z2[m] = b2[m];

    #pragma unroll 1
    for (int c = 0; c < 4; ++c) {
        const int j0 = c * 20;
        float z1c[20];
        #pragma unroll
        for (int j = 0; j < 20; ++j) z1c[j] = QWq[j0 + j];
        #pragma unroll
        for (int h = 0; h < H_; ++h) {
            float kh = kT[h][tt];
            const float* Wd = W1 + (192 + h) * J1 + j0;
            const float* Wb = W1 + (64 + h) * J1 + j0;
            const float* Wc = W1 + (128 + h) * J1 + j0;
            #pragma unroll
            for (int j = 0; j < 20; ++j)
                z1c[j] = fmaf(qk[h], Wd[j], fmaf(kh, Wb[j] - Wc[j], z1c[j]));
        }
        #pragma unroll
        for (int j = 0; j < 20; ++j) {
            float x = sigmoidf_(z1c[j]);
            const float* w2 = W2 + (j0 + j) * J2;
            #pragma unroll
            for (int m = 0; m < J2; ++m) z2[m] = fmaf(x, w2[m], z2[m]);
        }
    }

    float z3 = b3[0];
    #pragma unroll
    for (int m = 0; m < J2; ++m) z3 = fmaf(sigmoidf_(z2[m]), W3[m], z3);

    const int L = keys_length[b];
    float s = (tid < T_) ? ((tid < L) ? z3 : NEGV) * 0.125f : -3.0e38f;

    float mx = s;
    #pragma unroll
    for (int off = 32; off > 0; off >>= 1) mx = fmaxf(mx, __shfl_xor(mx, off));
    if ((tid & 63) == 0) red[tid >> 6] = mx;
    __syncthreads();
    mx = fmaxf(fmaxf(red[0], red[1]), fmaxf(red[2], red[3]));

    float e = (tid < T_) ? __expf(s - mx) : 0.0f;
    float sm = e;
    #pragma unroll
    for (int off = 32; off > 0; off >>= 1) sm += __shfl_xor(sm, off);
    __syncthreads();
    if ((tid & 63) == 0) red[4 + (tid >> 6)] = sm;
    __syncthreads();
    sm = red[4] + red[5] + red[6] + red[7];

    if (tid < T_) wsm[tid] = e / sm;
    __syncthreads();

    {
        int h = tid & 63, p = tid >> 6;
        float acc = 0.f;
        int t0 = p * 50;
        for (int t = t0; t < t0 + 50; ++t)
            acc = fmaf(wsm[t], kT[h][t], acc);
        part[tid] = acc;
    }
    __syncthreads();
    if (tid < 64) {
        out[bn * H_ + tid] = part[tid] + part[64 + tid] + part[128 + tid] + part[192 + tid];
    }
}

extern "C" void kernel_launch(void* const* d_in, const int* in_sizes, int n_in,
                              void* d_out, int out_size, void* d_ws, size_t ws_size,
                              hipStream_t stream) {
    const float* queries = (const float*)d_in[0];
    const float* keys    = (const float*)d_in[1];
    const int*   klen    = (const int*)  d_in[2];
    const float* W1 = (const float*)d_in[3];
    const float* b1 = (const float*)d_in[4];
    const float* W2 = (const float*)d_in[5];
    const float* b2 = (const float*)d_in[6];
    const float* W3 = (const float*)d_in[7];
    const float* b3 = (const float*)d_in[8];
    float* out = (float*)d_out;

    // ws layout (all 16B multiples):
    // QW   [2048*80 f32]    =    655,360 B
    // w1df [5120 f32]       =     20,480 B
    // wbcf [5120 f32]       =     20,480 B
    // kbf0 [26624 x 16B]    =  1,703,936 B
    // kbf1 [26624 x 16B]    =  1,703,936 B
    // Bnf  [2048*640 x 16B] = 20,971,520 B
    // W2F  [2304 u32]       =      9,216 B
    const size_t nkbf = (size_t)B_ * NTILE * 64;
    const size_t need = 655360 + 20480 + 20480 + 2 * 1703936 + 20971520 + 9216;

    if (ws_size >= need) {
        char* base = (char*)d_ws;
        float*  QW   = (float*)base;
        float*  w1df = (float*)(base + 655360);
        float*  wbcf = (float*)(base + 655360 + 20480);
        bf16x8* kbf0 = (bf16x8*)(base + 655360 + 40960);
        bf16x8* kbf1 = kbf0 + nkbf;
        bf16x8* Bnf  = kbf1 + nkbf;
        unsigned* W2F = (unsigned*)((char*)Bnf + 20971520);

        prep1<<<dim3(P_QW + P_WF + P_KB + P_W2), dim3(256), 0, stream>>>(
            queries, keys, W1, b1, W2, QW, w1df, wbcf, kbf0, kbf1, W2F);
        prep2<<<dim3(5120), dim3(256), 0, stream>>>(
            queries, w1df, wbcf, (uint4*)Bnf);
        attn_b4<<<dim3(B_ * N_), dim3(256), 0, stream>>>(
            keys, klen, QW, Bnf, kbf0, kbf1, (const bf16x8*)W2F, b2, W3, b3, out);
    } else {
        attn_nows<<<dim3(B_ * N_), dim3(256), 0, stream>>>(
            queries, keys, klen, W1, b1, W2, b2, W3, b3, out);
    }
}

// Round 9
// 98.384 us; speedup vs baseline: 1.0060x; 1.0040x over previous
//
#include <hip/hip_runtime.h>
#include <hip/hip_bf16.h>
#include <math.h>

#define B_  128
#define N_  16
#define T_  200
#define H_  64
#define J1  80
#define J2  40
#define NTILE 13
#define NEGV -4294967295.0f   // -2^32 + 1

typedef __attribute__((ext_vector_type(8))) short bf16x8;
typedef __attribute__((ext_vector_type(4))) float f32x4;

__device__ __forceinline__ float sigmoidf_(float x) {
    return 1.0f / (1.0f + __expf(-x));
}
// branch-free RNE f32->bf16 (finite inputs only)
__device__ __forceinline__ short f2b(float x) {
    unsigned u = __float_as_uint(x);
    return (short)((u + 0x7FFF + ((u >> 16) & 1)) >> 16);
}
__device__ __forceinline__ unsigned pack2(float a, float b) {
    return (unsigned)(unsigned short)f2b(a) | ((unsigned)(unsigned short)f2b(b) << 16);
}

// ---- prep1: QW | w1df/wbcf (frag-ordered f32) | kbf | W2F ---------------
#define P_QW 160
#define P_WF 3
#define P_KB 104
#define P_W2 9
__global__ void prep1(const float* __restrict__ queries,
                      const float* __restrict__ keys,
                      const float* __restrict__ W1,
                      const float* __restrict__ b1,
                      const float* __restrict__ W2,
                      float* __restrict__ QW,
                      float* __restrict__ w1df, float* __restrict__ wbcf,
                      bf16x8* __restrict__ kbf0, bf16x8* __restrict__ kbf1,
                      unsigned* __restrict__ W2F) {
    const int blk = blockIdx.x, tid = threadIdx.x;
    if (blk < P_QW) {
        int idx = blk * 256 + tid;                 // (bn, j/4)
        int bn = idx / 20, j = (idx % 20) * 4;
        float4 acc = *(const float4*)(b1 + j);
        const float* qp = queries + bn * H_;
        for (int h = 0; h < H_; ++h) {
            float qh = qp[h];
            float4 wa = *(const float4*)(W1 + h * J1 + j);
            float4 wc = *(const float4*)(W1 + (128 + h) * J1 + j);
            acc.x = fmaf(qh, wa.x + wc.x, acc.x);
            acc.y = fmaf(qh, wa.y + wc.y, acc.y);
            acc.z = fmaf(qh, wa.z + wc.z, acc.z);
            acc.w = fmaf(qh, wa.w + wc.w, acc.w);
        }
        *(float4*)(QW + bn * J1 + j) = acc;
    } else if (blk < P_QW + P_WF) {
        int idx = (blk - P_QW) * 256 + tid;        // (f,l), 640 threads
        if (idx < 640) {
            int l = idx & 63, f = idx >> 6;
            int j  = (f >> 1) * 16 + (l & 15);
            int h0 = (f & 1) * 32 + ((l >> 4) << 3);
            #pragma unroll
            for (int r = 0; r < 8; ++r) {
                int h = h0 + r;
                w1df[idx * 8 + r] = W1[(192 + h) * J1 + j];
                wbcf[idx * 8 + r] = W1[(64 + h) * J1 + j] - W1[(128 + h) * J1 + j];
            }
        }
    } else if (blk < P_QW + P_WF + P_KB) {
        int idx = (blk - P_QW - P_WF) * 256 + tid; // (b*13+mt)*64+l, exact
        int l  = idx & 63, bm = idx >> 6;
        int mt = bm % NTILE, b = bm / NTILE;
        int t  = mt * 16 + (l & 15); if (t > T_ - 1) t = T_ - 1;
        int rg = l >> 4;
        const float* kr = keys + ((size_t)(b * T_ + t)) * H_ + 8 * rg;
        float4 a0 = *(const float4*)(kr);
        float4 a1 = *(const float4*)(kr + 4);
        float4 a2 = *(const float4*)(kr + 32);
        float4 a3 = *(const float4*)(kr + 36);
        bf16x8 f0, f1;
        f0[0] = f2b(a0.x); f0[1] = f2b(a0.y); f0[2] = f2b(a0.z); f0[3] = f2b(a0.w);
        f0[4] = f2b(a1.x); f0[5] = f2b(a1.y); f0[6] = f2b(a1.z); f0[7] = f2b(a1.w);
        f1[0] = f2b(a2.x); f1[1] = f2b(a2.y); f1[2] = f2b(a2.z); f1[3] = f2b(a2.w);
        f1[4] = f2b(a3.x); f1[5] = f2b(a3.y); f1[6] = f2b(a3.z); f1[7] = f2b(a3.w);
        kbf0[idx] = f0; kbf1[idx] = f1;
    } else {
        int idx = (blk - P_QW - P_WF - P_KB) * 256 + tid;
        if (idx < 9 * 64 * 4) {
            int rp = idx & 3;
            int l  = (idx >> 2) & 63;
            int f  = idx >> 8;
            int m  = (f / 3) * 16 + (l & 15);
            int k0 = (f % 3) * 32 + 8 * (l >> 4) + 2 * rp;
            float a = (k0     < J1 && m < J2) ? W2[k0 * J2 + m]       : 0.0f;
            float b = (k0 + 1 < J1 && m < J2) ? W2[(k0 + 1) * J2 + m] : 0.0f;
            W2F[idx] = pack2(a, b);
        }
    }
}

// ---- prep2: Bnf[bn,f,l] = f2b(q[bn,h]*w1df + wbcf) — pure streaming -----
__global__ void prep2(const float* __restrict__ queries,
                      const float* __restrict__ w1df,
                      const float* __restrict__ wbcf,
                      uint4* __restrict__ Bnf) {
    int idx = blockIdx.x * 256 + threadIdx.x;      // 2048*640, exact
    int rem = idx % 640, bn = idx / 640;
    int f = rem >> 6, l = rem & 63;
    int h0 = (f & 1) * 32 + ((l >> 4) << 3);
    float4 w0 = *(const float4*)(w1df + rem * 8);
    float4 w1 = *(const float4*)(w1df + rem * 8 + 4);
    float4 c0 = *(const float4*)(wbcf + rem * 8);
    float4 c1 = *(const float4*)(wbcf + rem * 8 + 4);
    const float* qp = queries + bn * H_ + h0;
    float4 q0 = *(const float4*)(qp);
    float4 q1 = *(const float4*)(qp + 4);
    uint4 o;
    o.x = pack2(fmaf(q0.x, w0.x, c0.x), fmaf(q0.y, w0.y, c0.y));
    o.y = pack2(fmaf(q0.z, w0.z, c0.z), fmaf(q0.w, w0.w, c0.w));
    o.z = pack2(fmaf(q1.x, w1.x, c1.x), fmaf(q1.y, w1.y, c1.y));
    o.w = pack2(fmaf(q1.z, w1.z, c1.z), fmaf(q1.w, w1.w, c1.w));
    Bnf[idx] = o;                                  // coalesced 16B
}

// ---- main: block per bn, 4 waves; wave g owns tiles 4g..4g+3 as 2 pairs.
// FULL unrolls only (R8's partial `unroll 2` spilled acc to scratch:
// 113 MB WRITE_SIZE, rule #20). Each Bn fragment feeds 2 M-tiles.
__global__ __launch_bounds__(256, 4) void attn_b4(
        const float* __restrict__ keys, const int* __restrict__ keys_length,
        const float* __restrict__ QW,
        const bf16x8* __restrict__ Bnf,
        const bf16x8* __restrict__ kbf0, const bf16x8* __restrict__ kbf1,
        const bf16x8* __restrict__ W2F,
        const float* __restrict__ b2, const float* __restrict__ W3,
        const float* __restrict__ b3,
        float* __restrict__ out) {
    const int tid  = threadIdx.x;
    const int lane = tid & 63, wv = tid >> 6;            // 4 waves
    const int bn   = (blockIdx.x & 7) * 256 + (blockIdx.x >> 3);  // XCD swizzle
    const int b    = bn >> 4;
    const int cl   = lane & 15, rg = lane >> 4;

    __shared__ __align__(16) short X1[4][16][104];       // one slice per wave
    __shared__ float z3s[NTILE * 16];
    __shared__ float wsm[T_];
    __shared__ float part[256];
    __shared__ float red[8];

    // zero own-wave X1 k-pad cols 80..95 (wave-local, in-order LDS)
    #pragma unroll
    for (int i = 0; i < 4; ++i)
        X1[wv][rg + 4 * i][80 + cl] = 0;

    float qwv[5];
    #pragma unroll
    for (int nt = 0; nt < 5; ++nt) qwv[nt] = QW[bn * J1 + cl + 16 * nt];
    float b2v[3], w3v[3];
    #pragma unroll
    for (int nt = 0; nt < 3; ++nt) {
        int m  = cl + 16 * nt;
        int mc = m < J2 ? m : J2 - 1;
        b2v[nt] = b2[mc];
        w3v[nt] = (m < J2) ? W3[mc] : 0.0f;
    }
    const float b3v = b3[0];
    const bf16x8* bnp = Bnf + (size_t)bn * 640;

    #pragma unroll 1
    for (int p = 0; p < 2; ++p) {
        const int i0  = wv * 4 + 2 * p;
        const int mt0 = i0     < 12 ? i0     : 12;       // clamp: wave 3 redoes 12
        const int mt1 = i0 + 1 < 12 ? i0 + 1 : 12;       // (identical rewrite, benign)
        bf16x8 a00 = kbf0[(b * NTILE + mt0) * 64 + lane];
        bf16x8 a01 = kbf1[(b * NTILE + mt0) * 64 + lane];
        bf16x8 a10 = kbf0[(b * NTILE + mt1) * 64 + lane];
        bf16x8 a11 = kbf1[(b * NTILE + mt1) * 64 + lane];

        f32x4 acc[2][5];
        #pragma unroll
        for (int nt = 0; nt < 5; ++nt) {
            float qv = qwv[nt];
            acc[0][nt][0] = qv; acc[0][nt][1] = qv; acc[0][nt][2] = qv; acc[0][nt][3] = qv;
            acc[1][nt][0] = qv; acc[1][nt][1] = qv; acc[1][nt][2] = qv; acc[1][nt][3] = qv;
        }
        #pragma unroll
        for (int nt = 0; nt < 5; ++nt) {                 // FULL unroll: static idx
            bf16x8 b0 = bnp[(2 * nt + 0) * 64 + lane];   // L2, used by both tiles
            bf16x8 b1 = bnp[(2 * nt + 1) * 64 + lane];
            acc[0][nt] = __builtin_amdgcn_mfma_f32_16x16x32_bf16(a00, b0, acc[0][nt], 0, 0, 0);
            acc[1][nt] = __builtin_amdgcn_mfma_f32_16x16x32_bf16(a10, b0, acc[1][nt], 0, 0, 0);
            acc[0][nt] = __builtin_amdgcn_mfma_f32_16x16x32_bf16(a01, b1, acc[0][nt], 0, 0, 0);
            acc[1][nt] = __builtin_amdgcn_mfma_f32_16x16x32_bf16(a11, b1, acc[1][nt], 0, 0, 0);
        }

        // per-tile epilogue (X1 slice reused sequentially; in-order per wave)
        #pragma unroll
        for (int ti = 0; ti < 2; ++ti) {
            const int mte = (ti == 0) ? mt0 : mt1;
            #pragma unroll
            for (int nt = 0; nt < 5; ++nt)
                #pragma unroll
                for (int i = 0; i < 4; ++i)
                    X1[wv][rg * 4 + i][cl + 16 * nt] = f2b(sigmoidf_(acc[ti][nt][i]));

            f32x4 acc2[3];
            #pragma unroll
            for (int nt = 0; nt < 3; ++nt) {
                float bv = b2v[nt];
                acc2[nt][0] = bv; acc2[nt][1] = bv; acc2[nt][2] = bv; acc2[nt][3] = bv;
            }
            #pragma unroll
            for (int ks = 0; ks < 3; ++ks) {
                bf16x8 a2 = *(const bf16x8*)&X1[wv][cl][8 * rg + 32 * ks];
                acc2[0] = __builtin_amdgcn_mfma_f32_16x16x32_bf16(a2, W2F[(0 + ks) * 64 + lane], acc2[0], 0, 0, 0);
                acc2[1] = __builtin_amdgcn_mfma_f32_16x16x32_bf16(a2, W2F[(3 + ks) * 64 + lane], acc2[1], 0, 0, 0);
                acc2[2] = __builtin_amdgcn_mfma_f32_16x16x32_bf16(a2, W2F[(6 + ks) * 64 + lane], acc2[2], 0, 0, 0);
            }

            float p0 = 0.f, p1 = 0.f, p2 = 0.f, p3 = 0.f;
            #pragma unroll
            for (int nt = 0; nt < 3; ++nt) {
                p0 = fmaf(sigmoidf_(acc2[nt][0]), w3v[nt], p0);
                p1 = fmaf(sigmoidf_(acc2[nt][1]), w3v[nt], p1);
                p2 = fmaf(sigmoidf_(acc2[nt][2]), w3v[nt], p2);
                p3 = fmaf(sigmoidf_(acc2[nt][3]), w3v[nt], p3);
            }
            #pragma unroll
            for (int off = 1; off < 16; off <<= 1) {
                p0 += __shfl_xor(p0, off);
                p1 += __shfl_xor(p1, off);
                p2 += __shfl_xor(p2, off);
                p3 += __shfl_xor(p3, off);
            }
            if (cl == 0) {
                z3s[mte * 16 + rg * 4 + 0] = p0 + b3v;
                z3s[mte * 16 + rg * 4 + 1] = p1 + b3v;
                z3s[mte * 16 + rg * 4 + 2] = p2 + b3v;
                z3s[mte * 16 + rg * 4 + 3] = p3 + b3v;
            }
        }
    }
    __syncthreads();

    // ---- mask + scale + softmax (thread tid owns t = tid) ----
    const int L = keys_length[b];
    float s = (tid < T_) ? ((tid < L) ? z3s[tid] : NEGV) * 0.125f : -3.0e38f;

    float mx = s;
    #pragma unroll
    for (int off = 32; off > 0; off >>= 1) mx = fmaxf(mx, __shfl_xor(mx, off));
    if ((tid & 63) == 0) red[tid >> 6] = mx;
    __syncthreads();
    mx = fmaxf(fmaxf(red[0], red[1]), fmaxf(red[2], red[3]));

    float e = (tid < T_) ? __expf(s - mx) : 0.0f;
    float sm = e;
    #pragma unroll
    for (int off = 32; off > 0; off >>= 1) sm += __shfl_xor(sm, off);
    __syncthreads();
    if ((tid & 63) == 0) red[4 + (tid >> 6)] = sm;
    __syncthreads();
    sm = red[4] + red[5] + red[6] + red[7];

    if (tid < T_) wsm[tid] = e / sm;
    __syncthreads();

    // ---- out[h] = sum_t w[t] * keys[b][t][h] (L2-hot, coalesced) ----
    const float* kb = keys + (size_t)b * T_ * H_;
    {
        int h = tid & 63, pw = tid >> 6;
        float acc = 0.f;
        int tb = pw * 50;
        #pragma unroll 5
        for (int t = tb; t < tb + 50; ++t)
            acc = fmaf(wsm[t], kb[(size_t)t * H_ + h], acc);
        part[tid] = acc;
    }
    __syncthreads();
    if (tid < 64) {
        out[bn * H_ + tid] = part[tid] + part[64 + tid] + part[128 + tid] + part[192 + tid];
    }
}

// --- fallback (no workspace): round-3 verified pure-VALU kernel ----------
__global__ __launch_bounds__(256, 3) void attn_nows(
        const float* __restrict__ queries, const float* __restrict__ keys,
        const int*   __restrict__ keys_length,
        const float* __restrict__ W1, const float* __restrict__ b1,
        const float* __restrict__ W2, const float* __restrict__ b2,
        const float* __restrict__ W3, const float* __restrict__ b3,
        float* __restrict__ out) {
    const int tid = threadIdx.x;
    const int bn = (blockIdx.x & 7) * 256 + (blockIdx.x >> 3);
    const int b  = bn >> 4;

    __shared__ float kT[H_][T_ + 1];
    __shared__ float wsm[T_];
    __shared__ float part[256];
    __shared__ float red[8];
    __shared__ float QWq[J1];

    for (int idx = tid; idx < T_ * H_; idx += 256) {
        int t = idx >> 6, h = idx & 63;
        kT[h][t] = keys[(b * T_ + t) * H_ + h];
    }
    if (tid < J1) {
        float acc = b1[tid];
        const float* qp = queries + bn * H_;
        for (int h = 0; h < H_; ++h)
            acc = fmaf(qp[h], W1[h * J1 + tid] + W1[(128 + h) * J1 + tid], acc);
        QWq[tid] = acc;
    }
    __syncthreads();

    const int tt = (tid < T_) ? tid : 0;
    const float* qp = queries + bn * H_;

    float qk[H_];
    #pragma unroll
    for (int h = 0; h < H_; ++h) qk[h] = qp[h] * kT[h][tt];

    float z2[J2];
    #pragma unroll
    for (int m = 0; m < J2; ++m) z2[m] = b2[m];

    #pragma unroll 1
    for (int c = 0; c < 4; ++c) {
        const int j0 = c * 20;
        float z1c[20];
        #pragma unroll
        for (int j = 0; j < 20; ++j) z1c[j] = QWq[j0 + j];
        #pragma unroll
        for (int h = 0; h < H_; ++h) {
            float kh = kT[h][tt];
            const float* Wd = W1 + (192 + h) * J1 + j0;
            const float* Wb = W1 + (64 + h) * J1 + j0;
            const float* Wc = W1 + (128 + h) * J1 + j0;
            #pragma unroll
            for (int j = 0; j < 20; ++j)
                z1c[j] = fmaf(qk[h], Wd[j], fmaf(kh, Wb[j] - Wc[j], z1c[j]));
        }
        #pragma unroll
        for (int j = 0; j < 20; ++j) {
            float x = sigmoidf_(z1c[j]);
            const float* w2 = W2 + (j0 + j) * J2;
            #pragma unroll
            for (int m = 0; m < J2; ++m) z2[m] = fmaf(x, w2[m], z2[m]);
        }
    }

    float z3 = b3[0];
    #pragma unroll
    for (int m = 0; m < J2; ++m) z3 = fmaf(sigmoidf_(z2[m]), W3[m], z3);

    const int L = keys_length[b];
    float s = (tid < T_) ? ((tid < L) ? z3 : NEGV) * 0.125f : -3.0e38f;

    float mx = s;
    #pragma unroll
    for (int off = 32; off > 0; off >>= 1) mx = fmaxf(mx, __shfl_xor(mx, off));
    if ((tid & 63) == 0) red[tid >> 6] = mx;
    __syncthreads();
    mx = fmaxf(fmaxf(red[0], red[1]), fmaxf(red[2], red[3]));

    float e = (tid < T_) ? __expf(s - mx) : 0.0f;
    float sm = e;
    #pragma unroll
    for (int off = 32; off > 0; off >>= 1) sm += __shfl_xor(sm, off);
    __syncthreads();
    if ((tid & 63) == 0) red[4 + (tid >> 6)] = sm;
    __syncthreads();
    sm = red[4] + red[5] + red[6] + red[7];

    if (tid < T_) wsm[tid] = e / sm;
    __syncthreads();

    {
        int h = tid & 63, p = tid >> 6;
        float acc = 0.f;
        int t0 = p * 50;
        for (int t = t0; t < t0 + 50; ++t)
            acc = fmaf(wsm[t], kT[h][t], acc);
        part[tid] = acc;
    }
    __syncthreads();
    if (tid < 64) {
        out[bn * H_ + tid] = part[tid] + part[64 + tid] + part[128 + tid] + part[192 + tid];
    }
}

extern "C" void kernel_launch(void* const* d_in, const int* in_sizes, int n_in,
                              void* d_out, int out_size, void* d_ws, size_t ws_size,
                              hipStream_t stream) {
    const float* queries = (const float*)d_in[0];
    const float* keys    = (const float*)d_in[1];
    const int*   klen    = (const int*)  d_in[2];
    const float* W1 = (const float*)d_in[3];
    const float* b1 = (const float*)d_in[4];
    const float* W2 = (const float*)d_in[5];
    const float* b2 = (const float*)d_in[6];
    const float* W3 = (const float*)d_in[7];
    const float* b3 = (const float*)d_in[8];
    float* out = (float*)d_out;

    // ws layout (all 16B multiples):
    // QW   [2048*80 f32]    =    655,360 B
    // w1df [5120 f32]       =     20,480 B
    // wbcf [5120 f32]       =     20,480 B
    // kbf0 [26624 x 16B]    =  1,703,936 B
    // kbf1 [26624 x 16B]    =  1,703,936 B
    // Bnf  [2048*640 x 16B] = 20,971,520 B
    // W2F  [2304 u32]       =      9,216 B
    const size_t nkbf = (size_t)B_ * NTILE * 64;
    const size_t need = 655360 + 20480 + 20480 + 2 * 1703936 + 20971520 + 9216;

    if (ws_size >= need) {
        char* base = (char*)d_ws;
        float*  QW   = (float*)base;
        float*  w1df = (float*)(base + 655360);
        float*  wbcf = (float*)(base + 655360 + 20480);
        bf16x8* kbf0 = (bf16x8*)(base + 655360 + 40960);
        bf16x8* kbf1 = kbf0 + nkbf;
        bf16x8* Bnf  = kbf1 + nkbf;
        unsigned* W2F = (unsigned*)((char*)Bnf + 20971520);

        prep1<<<dim3(P_QW + P_WF + P_KB + P_W2), dim3(256), 0, stream>>>(
            queries, keys, W1, b1, W2, QW, w1df, wbcf, kbf0, kbf1, W2F);
        prep2<<<dim3(5120), dim3(256), 0, stream>>>(
            queries, w1df, wbcf, (uint4*)Bnf);
        attn_b4<<<dim3(B_ * N_), dim3(256), 0, stream>>>(
            keys, klen, QW, Bnf, kbf0, kbf1, (const bf16x8*)W2F, b2, W3, b3, out);
    } else {
        attn_nows<<<dim3(B_ * N_), dim3(256), 0, stream>>>(
            queries, keys, klen, W1, b1, W2, b2, W3, b3, out);
    }
}

// Round 10
// 70.565 us; speedup vs baseline: 1.4025x; 1.3942x over previous
//
#include <hip/hip_runtime.h>
#include <hip/hip_bf16.h>
#include <math.h>

#define B_  128
#define N_  16
#define T_  200
#define H_  64
#define J1  80
#define J2  40
#define NTILE 13
#define ZSTR  208              // per-bn score stride (13*16)
#define NEGV -4294967295.0f   // -2^32 + 1

typedef __attribute__((ext_vector_type(8))) short bf16x8;
typedef __attribute__((ext_vector_type(4))) float f32x4;

__device__ __forceinline__ float sigmoidf_(float x) {
    return 1.0f / (1.0f + __expf(-x));
}
// branch-free RNE f32->bf16 (finite inputs only)
__device__ __forceinline__ short f2b(float x) {
    unsigned u = __float_as_uint(x);
    return (short)((u + 0x7FFF + ((u >> 16) & 1)) >> 16);
}
__device__ __forceinline__ unsigned pack2(float a, float b) {
    return (unsigned)(unsigned short)f2b(a) | ((unsigned)(unsigned short)f2b(b) << 16);
}

// ---- prep1: QW | w1df/wbcf (frag-ordered f32) | kbf | W2F ---------------
#define P_QW 160
#define P_WF 3
#define P_KB 104
#define P_W2 9
__global__ void prep1(const float* __restrict__ queries,
                      const float* __restrict__ keys,
                      const float* __restrict__ W1,
                      const float* __restrict__ b1,
                      const float* __restrict__ W2,
                      float* __restrict__ QW,
                      float* __restrict__ w1df, float* __restrict__ wbcf,
                      bf16x8* __restrict__ kbf0, bf16x8* __restrict__ kbf1,
                      unsigned* __restrict__ W2F) {
    const int blk = blockIdx.x, tid = threadIdx.x;
    if (blk < P_QW) {
        int idx = blk * 256 + tid;                 // (bn, j/4)
        int bn = idx / 20, j = (idx % 20) * 4;
        float4 acc = *(const float4*)(b1 + j);
        const float* qp = queries + bn * H_;
        for (int h = 0; h < H_; ++h) {
            float qh = qp[h];
            float4 wa = *(const float4*)(W1 + h * J1 + j);
            float4 wc = *(const float4*)(W1 + (128 + h) * J1 + j);
            acc.x = fmaf(qh, wa.x + wc.x, acc.x);
            acc.y = fmaf(qh, wa.y + wc.y, acc.y);
            acc.z = fmaf(qh, wa.z + wc.z, acc.z);
            acc.w = fmaf(qh, wa.w + wc.w, acc.w);
        }
        *(float4*)(QW + bn * J1 + j) = acc;
    } else if (blk < P_QW + P_WF) {
        int idx = (blk - P_QW) * 256 + tid;        // (f,l), 640 threads
        if (idx < 640) {
            int l = idx & 63, f = idx >> 6;
            int j  = (f >> 1) * 16 + (l & 15);
            int h0 = (f & 1) * 32 + ((l >> 4) << 3);
            #pragma unroll
            for (int r = 0; r < 8; ++r) {
                int h = h0 + r;
                w1df[idx * 8 + r] = W1[(192 + h) * J1 + j];
                wbcf[idx * 8 + r] = W1[(64 + h) * J1 + j] - W1[(128 + h) * J1 + j];
            }
        }
    } else if (blk < P_QW + P_WF + P_KB) {
        int idx = (blk - P_QW - P_WF) * 256 + tid; // (b*13+mt)*64+l, exact
        int l  = idx & 63, bm = idx >> 6;
        int mt = bm % NTILE, b = bm / NTILE;
        int t  = mt * 16 + (l & 15); if (t > T_ - 1) t = T_ - 1;
        int rg = l >> 4;
        const float* kr = keys + ((size_t)(b * T_ + t)) * H_ + 8 * rg;
        float4 a0 = *(const float4*)(kr);
        float4 a1 = *(const float4*)(kr + 4);
        float4 a2 = *(const float4*)(kr + 32);
        float4 a3 = *(const float4*)(kr + 36);
        bf16x8 f0, f1;
        f0[0] = f2b(a0.x); f0[1] = f2b(a0.y); f0[2] = f2b(a0.z); f0[3] = f2b(a0.w);
        f0[4] = f2b(a1.x); f0[5] = f2b(a1.y); f0[6] = f2b(a1.z); f0[7] = f2b(a1.w);
        f1[0] = f2b(a2.x); f1[1] = f2b(a2.y); f1[2] = f2b(a2.z); f1[3] = f2b(a2.w);
        f1[4] = f2b(a3.x); f1[5] = f2b(a3.y); f1[6] = f2b(a3.z); f1[7] = f2b(a3.w);
        kbf0[idx] = f0; kbf1[idx] = f1;
    } else {
        int idx = (blk - P_QW - P_WF - P_KB) * 256 + tid;
        if (idx < 9 * 64 * 4) {
            int rp = idx & 3;
            int l  = (idx >> 2) & 63;
            int f  = idx >> 8;
            int m  = (f / 3) * 16 + (l & 15);
            int k0 = (f % 3) * 32 + 8 * (l >> 4) + 2 * rp;
            float a = (k0     < J1 && m < J2) ? W2[k0 * J2 + m]       : 0.0f;
            float b = (k0 + 1 < J1 && m < J2) ? W2[(k0 + 1) * J2 + m] : 0.0f;
            W2F[idx] = pack2(a, b);
        }
    }
}

// ---- prep2: Bnf[bn,f,l] = f2b(q[bn,h]*w1df + wbcf) — pure streaming -----
__global__ void prep2(const float* __restrict__ queries,
                      const float* __restrict__ w1df,
                      const float* __restrict__ wbcf,
                      uint4* __restrict__ Bnf) {
    int idx = blockIdx.x * 256 + threadIdx.x;      // 2048*640, exact
    int rem = idx % 640, bn = idx / 640;
    int f = rem >> 6, l = rem & 63;
    int h0 = (f & 1) * 32 + ((l >> 4) << 3);
    float4 w0 = *(const float4*)(w1df + rem * 8);
    float4 w1 = *(const float4*)(w1df + rem * 8 + 4);
    float4 c0 = *(const float4*)(wbcf + rem * 8);
    float4 c1 = *(const float4*)(wbcf + rem * 8 + 4);
    const float* qp = queries + bn * H_ + h0;
    float4 q0 = *(const float4*)(qp);
    float4 q1 = *(const float4*)(qp + 4);
    uint4 o;
    o.x = pack2(fmaf(q0.x, w0.x, c0.x), fmaf(q0.y, w0.y, c0.y));
    o.y = pack2(fmaf(q0.z, w0.z, c0.z), fmaf(q0.w, w0.w, c0.w));
    o.z = pack2(fmaf(q1.x, w1.x, c1.x), fmaf(q1.y, w1.y, c1.y));
    o.w = pack2(fmaf(q1.z, w1.z, c1.z), fmaf(q1.w, w1.w, c1.w));
    Bnf[idx] = o;                                  // coalesced 16B
}

// ---- scores: ONE WAVE per (bn, mt) job; no barriers, pure dataflow ------
// 26624 jobs = 6656 blocks x 4 waves. NO min-waves bound: gfx950's unified
// VGPR/AGPR file means (256,4) caps the combined budget at 128 and spills
// the MFMA accumulators to scratch (R8/R9: 113 MB WRITE_SIZE, VGPR=64).
__global__ __launch_bounds__(256) void score_mfma(
        const float* __restrict__ QW,
        const bf16x8* __restrict__ Bnf,
        const bf16x8* __restrict__ kbf0, const bf16x8* __restrict__ kbf1,
        const bf16x8* __restrict__ W2F,
        const float* __restrict__ b2, const float* __restrict__ W3,
        const float* __restrict__ b3,
        float* __restrict__ z3ws) {
    const int tid  = threadIdx.x;
    const int lane = tid & 63, wv = tid >> 6;
    // bijective XCD swizzle: 6656 = 8*832 -> same-bn jobs share an XCD L2
    const int bid  = (blockIdx.x & 7) * 832 + (blockIdx.x >> 3);
    const int job  = bid * 4 + wv;
    const int bn   = job / NTILE, mt = job % NTILE;
    const int b    = bn >> 4;
    const int cl   = lane & 15, rg = lane >> 4;

    __shared__ __align__(16) short X1[4][16][104];   // per-wave slice, no barrier

    // zero k-pad cols 80..95 of own-wave slice (rows 0..15)
    #pragma unroll
    for (int i = 0; i < 4; ++i)
        X1[wv][rg + 4 * i][80 + cl] = 0;

    // layer-1 operands (single-use, coalesced, L2-hot)
    bf16x8 a0 = kbf0[(b * NTILE + mt) * 64 + lane];
    bf16x8 a1 = kbf1[(b * NTILE + mt) * 64 + lane];
    bf16x8 bfr[10];
    #pragma unroll
    for (int f = 0; f < 10; ++f) bfr[f] = Bnf[(size_t)bn * 640 + f * 64 + lane];
    float qwv[5];
    #pragma unroll
    for (int nt = 0; nt < 5; ++nt) qwv[nt] = QW[bn * J1 + cl + 16 * nt];

    // layer 1: Z1 = K @ Bn + QW
    f32x4 acc[5];
    #pragma unroll
    for (int nt = 0; nt < 5; ++nt) {
        float qv = qwv[nt];
        acc[nt][0] = qv; acc[nt][1] = qv; acc[nt][2] = qv; acc[nt][3] = qv;
    }
    #pragma unroll
    for (int nt = 0; nt < 5; ++nt) {
        acc[nt] = __builtin_amdgcn_mfma_f32_16x16x32_bf16(a0, bfr[nt * 2 + 0], acc[nt], 0, 0, 0);
        acc[nt] = __builtin_amdgcn_mfma_f32_16x16x32_bf16(a1, bfr[nt * 2 + 1], acc[nt], 0, 0, 0);
    }

    // sigmoid -> X1 (C layout: row = rg*4+i, col = cl+16nt)
    #pragma unroll
    for (int nt = 0; nt < 5; ++nt)
        #pragma unroll
        for (int i = 0; i < 4; ++i)
            X1[wv][rg * 4 + i][cl + 16 * nt] = f2b(sigmoidf_(acc[nt][i]));

    // layer-2 operands (after layer 1: bounds live-range overlap)
    bf16x8 w2f[9];
    #pragma unroll
    for (int f = 0; f < 9; ++f) w2f[f] = W2F[f * 64 + lane];
    float b2v[3], w3v[3];
    #pragma unroll
    for (int nt = 0; nt < 3; ++nt) {
        int m  = cl + 16 * nt;
        int mc = m < J2 ? m : J2 - 1;
        b2v[nt] = b2[mc];
        w3v[nt] = (m < J2) ? W3[mc] : 0.0f;
    }
    const float b3v = b3[0];

    // layer 2: Z2 = X1 @ W2 + b2
    f32x4 acc2[3];
    #pragma unroll
    for (int nt = 0; nt < 3; ++nt) {
        float bv = b2v[nt];
        acc2[nt][0] = bv; acc2[nt][1] = bv; acc2[nt][2] = bv; acc2[nt][3] = bv;
    }
    #pragma unroll
    for (int ks = 0; ks < 3; ++ks) {
        bf16x8 a2 = *(const bf16x8*)&X1[wv][cl][8 * rg + 32 * ks];
        acc2[0] = __builtin_amdgcn_mfma_f32_16x16x32_bf16(a2, w2f[0 + ks], acc2[0], 0, 0, 0);
        acc2[1] = __builtin_amdgcn_mfma_f32_16x16x32_bf16(a2, w2f[3 + ks], acc2[1], 0, 0, 0);
        acc2[2] = __builtin_amdgcn_mfma_f32_16x16x32_bf16(a2, w2f[6 + ks], acc2[2], 0, 0, 0);
    }

    // layer 3 + 16-lane reduce
    float p0 = 0.f, p1 = 0.f, p2 = 0.f, p3 = 0.f;
    #pragma unroll
    for (int nt = 0; nt < 3; ++nt) {
        p0 = fmaf(sigmoidf_(acc2[nt][0]), w3v[nt], p0);
        p1 = fmaf(sigmoidf_(acc2[nt][1]), w3v[nt], p1);
        p2 = fmaf(sigmoidf_(acc2[nt][2]), w3v[nt], p2);
        p3 = fmaf(sigmoidf_(acc2[nt][3]), w3v[nt], p3);
    }
    #pragma unroll
    for (int off = 1; off < 16; off <<= 1) {
        p0 += __shfl_xor(p0, off);
        p1 += __shfl_xor(p1, off);
        p2 += __shfl_xor(p2, off);
        p3 += __shfl_xor(p3, off);
    }
    if (cl == 0) {
        float* zp = z3ws + (size_t)bn * ZSTR + mt * 16 + rg * 4;
        zp[0] = p0 + b3v; zp[1] = p1 + b3v; zp[2] = p2 + b3v; zp[3] = p3 + b3v;
    }
}

// ---- softmax + weighted sum: block per bn (verified R6 code) ------------
__global__ __launch_bounds__(256) void softmax_pv(
        const float* __restrict__ keys, const int* __restrict__ keys_length,
        const float* __restrict__ z3ws, float* __restrict__ out) {
    const int tid = threadIdx.x;
    const int bn  = (blockIdx.x & 7) * 256 + (blockIdx.x >> 3);  // XCD swizzle
    const int b   = bn >> 4;

    __shared__ float wsm[T_];
    __shared__ float part[256];
    __shared__ float red[8];

    const int L = keys_length[b];
    float s = (tid < T_) ? ((tid < L) ? z3ws[(size_t)bn * ZSTR + tid] : NEGV) * 0.125f
                         : -3.0e38f;

    float mx = s;
    #pragma unroll
    for (int off = 32; off > 0; off >>= 1) mx = fmaxf(mx, __shfl_xor(mx, off));
    if ((tid & 63) == 0) red[tid >> 6] = mx;
    __syncthreads();
    mx = fmaxf(fmaxf(red[0], red[1]), fmaxf(red[2], red[3]));

    float e = (tid < T_) ? __expf(s - mx) : 0.0f;
    float sm = e;
    #pragma unroll
    for (int off = 32; off > 0; off >>= 1) sm += __shfl_xor(sm, off);
    __syncthreads();
    if ((tid & 63) == 0) red[4 + (tid >> 6)] = sm;
    __syncthreads();
    sm = red[4] + red[5] + red[6] + red[7];

    if (tid < T_) wsm[tid] = e / sm;
    __syncthreads();

    const float* kb = keys + (size_t)b * T_ * H_;
    {
        int h = tid & 63, p = tid >> 6;
        float acc = 0.f;
        int tb = p * 50;
        #pragma unroll 5
        for (int t = tb; t < tb + 50; ++t)
            acc = fmaf(wsm[t], kb[(size_t)t * H_ + h], acc);
        part[tid] = acc;
    }
    __syncthreads();
    if (tid < 64) {
        out[bn * H_ + tid] = part[tid] + part[64 + tid] + part[128 + tid] + part[192 + tid];
    }
}

// --- fallback (no workspace): round-3 verified pure-VALU kernel ----------
__global__ __launch_bounds__(256, 3) void attn_nows(
        const float* __restrict__ queries, const float* __restrict__ keys,
        const int*   __restrict__ keys_length,
        const float* __restrict__ W1, const float* __restrict__ b1,
        const float* __restrict__ W2, const float* __restrict__ b2,
        const float* __restrict__ W3, const float* __restrict__ b3,
        float* __restrict__ out) {
    const int tid = threadIdx.x;
    const int bn = (blockIdx.x & 7) * 256 + (blockIdx.x >> 3);
    const int b  = bn >> 4;

    __shared__ float kT[H_][T_ + 1];
    __shared__ float wsm[T_];
    __shared__ float part[256];
    __shared__ float red[8];
    __shared__ float QWq[J1];

    for (int idx = tid; idx < T_ * H_; idx += 256) {
        int t = idx >> 6, h = idx & 63;
        kT[h][t] = keys[(b * T_ + t) * H_ + h];
    }
    if (tid < J1) {
        float acc = b1[tid];
        const float* qp = queries + bn * H_;
        for (int h = 0; h < H_; ++h)
            acc = fmaf(qp[h], W1[h * J1 + tid] + W1[(128 + h) * J1 + tid], acc);
        QWq[tid] = acc;
    }
    __syncthreads();

    const int tt = (tid < T_) ? tid : 0;
    const float* qp = queries + bn * H_;

    float qk[H_];
    #pragma unroll
    for (int h = 0; h < H_; ++h) qk[h] = qp[h] * kT[h][tt];

    float z2[J2];
    #pragma unroll
    for (int m = 0; m < J2; ++m) z2[m] = b2[m];

    #pragma unroll 1
    for (int c = 0; c < 4; ++c) {
        const int j0 = c * 20;
        float z1c[20];
        #pragma unroll
        for (int j = 0; j < 20; ++j) z1c[j] = QWq[j0 + j];
        #pragma unroll
        for (int h = 0; h < H_; ++h) {
            float kh = kT[h][tt];
            const float* Wd = W1 + (192 + h) * J1 + j0;
            const float* Wb = W1 + (64 + h) * J1 + j0;
            const float* Wc = W1 + (128 + h) * J1 + j0;
            #pragma unroll
            for (int j = 0; j < 20; ++j)
                z1c[j] = fmaf(qk[h], Wd[j], fmaf(kh, Wb[j] - Wc[j], z1c[j]));
        }
        #pragma unroll
        for (int j = 0; j < 20; ++j) {
            float x = sigmoidf_(z1c[j]);
            const float* w2 = W2 + (j0 + j) * J2;
            #pragma unroll
            for (int m = 0; m < J2; ++m) z2[m] = fmaf(x, w2[m], z2[m]);
        }
    }

    float z3 = b3[0];
    #pragma unroll
    for (int m = 0; m < J2; ++m) z3 = fmaf(sigmoidf_(z2[m]), W3[m], z3);

    const int L = keys_length[b];
    float s = (tid < T_) ? ((tid < L) ? z3 : NEGV) * 0.125f : -3.0e38f;

    float mx = s;
    #pragma unroll
    for (int off = 32; off > 0; off >>= 1) mx = fmaxf(mx, __shfl_xor(mx, off));
    if ((tid & 63) == 0) red[tid >> 6] = mx;
    __syncthreads();
    mx = fmaxf(fmaxf(red[0], red[1]), fmaxf(red[2], red[3]));

    float e = (tid < T_) ? __expf(s - mx) : 0.0f;
    float sm = e;
    #pragma unroll
    for (int off = 32; off > 0; off >>= 1) sm += __shfl_xor(sm, off);
    __syncthreads();
    if ((tid & 63) == 0) red[4 + (tid >> 6)] = sm;
    __syncthreads();
    sm = red[4] + red[5] + red[6] + red[7];

    if (tid < T_) wsm[tid] = e / sm;
    __syncthreads();

    {
        int h = tid & 63, p = tid >> 6;
        float acc = 0.f;
        int t0 = p * 50;
        for (int t = t0; t < t0 + 50; ++t)
            acc = fmaf(wsm[t], kT[h][t], acc);
        part[tid] = acc;
    }
    __syncthreads();
    if (tid < 64) {
        out[bn * H_ + tid] = part[tid] + part[64 + tid] + part[128 + tid] + part[192 + tid];
    }
}

extern "C" void kernel_launch(void* const* d_in, const int* in_sizes, int n_in,
                              void* d_out, int out_size, void* d_ws, size_t ws_size,
                              hipStream_t stream) {
    const float* queries = (const float*)d_in[0];
    const float* keys    = (const float*)d_in[1];
    const int*   klen    = (const int*)  d_in[2];
    const float* W1 = (const float*)d_in[3];
    const float* b1 = (const float*)d_in[4];
    const float* W2 = (const float*)d_in[5];
    const float* b2 = (const float*)d_in[6];
    const float* W3 = (const float*)d_in[7];
    const float* b3 = (const float*)d_in[8];
    float* out = (float*)d_out;

    // ws layout (all 16B multiples):
    // QW   [2048*80 f32]    =    655,360 B
    // w1df [5120 f32]       =     20,480 B
    // wbcf [5120 f32]       =     20,480 B
    // kbf0 [26624 x 16B]    =  1,703,936 B
    // kbf1 [26624 x 16B]    =  1,703,936 B
    // Bnf  [2048*640 x 16B] = 20,971,520 B
    // W2F  [2304 u32]       =      9,216 B
    // z3   [2048*208 f32]   =  1,703,936 B
    const size_t nkbf = (size_t)B_ * NTILE * 64;
    const size_t need = 655360 + 20480 + 20480 + 2 * 1703936 + 20971520 + 9216
                      + 1703936;

    if (ws_size >= need) {
        char* base = (char*)d_ws;
        float*  QW   = (float*)base;
        float*  w1df = (float*)(base + 655360);
        float*  wbcf = (float*)(base + 655360 + 20480);
        bf16x8* kbf0 = (bf16x8*)(base + 655360 + 40960);
        bf16x8* kbf1 = kbf0 + nkbf;
        bf16x8* Bnf  = kbf1 + nkbf;
        unsigned* W2F = (unsigned*)((char*)Bnf + 20971520);
        float*  z3ws = (float*)((char*)W2F + 9216);

        prep1<<<dim3(P_QW + P_WF + P_KB + P_W2), dim3(256), 0, stream>>>(
            queries, keys, W1, b1, W2, QW, w1df, wbcf, kbf0, kbf1, W2F);
        prep2<<<dim3(5120), dim3(256), 0, stream>>>(
            queries, w1df, wbcf, (uint4*)Bnf);
        score_mfma<<<dim3(6656), dim3(256), 0, stream>>>(
            QW, Bnf, kbf0, kbf1, (const bf16x8*)W2F, b2, W3, b3, z3ws);
        softmax_pv<<<dim3(B_ * N_), dim3(256), 0, stream>>>(keys, klen, z3ws, out);
    } else {
        attn_nows<<<dim3(B_ * N_), dim3(256), 0, stream>>>(
            queries, keys, klen, W1, b1, W2, b2, W3, b3, out);
    }
}